// Round 9
// baseline (62.704 us; speedup 1.0000x reference)
//
#include <hip/hip_runtime.h>

typedef __attribute__((ext_vector_type(4))) float f32x4;
typedef __attribute__((ext_vector_type(2))) long i64x2;

#define SCALE 262144.0f                 // 2^18 codebook prescale
#define NEG2S -524288.0f                // -2 * SCALE
#define INV_S2 1.4551915228366852e-11f  // 2^-36, exact

static __device__ __forceinline__ unsigned umin2(unsigned a, unsigned b) { return a < b ? a : b; }

// exact e4m3fn decode (bias 7, 3-bit mantissa, denormals at 2^-9)
static __device__ __forceinline__ float dec_e4m3(unsigned b) {
  int e = (b >> 3) & 15, m = b & 7;
  float v = e ? ldexpf((float)(8 + m), e - 10) : ldexpf((float)m, -9);
  return (b & 0x80) ? -v : v;
}

// ---------------- Kernel 1: prep ----------------
// codebook fp32 -> (x SCALE) -> fp8 e4m3, stored PERMUTED: for k = ks*32+hi*8+j,
// byte position = hi*64 + ks*8 + j  (MFMA B-fragment order).
// norms[code] = sum(dec(fp8)^2) fp32 (exact, consistent with MFMA dot).
__global__ void vq_prep(const float* __restrict__ cb,
                        float* __restrict__ norms,
                        unsigned char* __restrict__ cbh,
                        float* __restrict__ loss_out) {
  if (blockIdx.x == 0 && threadIdx.x == 0) *loss_out = 0.0f;
  const int lane = threadIdx.x & 63;
  const int code = (blockIdx.x * blockDim.x + threadIdx.x) >> 6;  // one wave per code
  const f32x4 v = ((const f32x4*)(cb + (long)code * 256))[lane];  // k = 4*lane .. +3
  unsigned w = __builtin_amdgcn_cvt_pk_fp8_f32(v[0] * SCALE, v[1] * SCALE, 0, false);
  w = __builtin_amdgcn_cvt_pk_fp8_f32(v[2] * SCALE, v[3] * SCALE, w, true);
  float n = 0.f;
#pragma unroll
  for (int j = 0; j < 4; ++j) {
    float d = dec_e4m3((w >> (8 * j)) & 0xFFu);
    n = __builtin_fmaf(d, d, n);
  }
  // k0 = 4*lane: ks = lane>>3, hi = (lane>>1)&3, j0 = (lane&1)*4
  const int newpos = ((lane >> 1) & 3) * 64 + (lane >> 3) * 8 + (lane & 1) * 4;
  *(unsigned*)(cbh + (long)code * 256 + newpos) = w;
#pragma unroll
  for (int m = 1; m < 64; m <<= 1) n += __shfl_xor(n, m);
  if (lane == 0) norms[code] = n;
}

// ---------------- Kernel 2: main ----------------
// Codebook-stationary: each of 8 waves holds 128 codes (fp8 B-frags, 128 VGPR)
// for the whole kernel; X streams through LDS in 16-row fp8 tiles.
#define NTHR 512
#define RPB 256    // rows per block
#define NTILE 16   // RPB / 16

__global__ __launch_bounds__(NTHR, 2)
void vq_main(const float* __restrict__ X,
             const float* __restrict__ CB,
             const float* __restrict__ norms_g,
             const unsigned char* __restrict__ cbh,
             float* __restrict__ out,
             float* __restrict__ loss_out,
             float lscale) {
  __shared__ __attribute__((aligned(16))) unsigned char Xs[2][4096];  // 2 x (16 rows x 256B fp8)
  __shared__ unsigned mgAll[NTILE][8][16];  // per-tile per-wave best keys (8 KiB)
  __shared__ unsigned idxArr[RPB];
  __shared__ float wsumX[8], wsumS[8];

  const int t = threadIdx.x;
  const int lane = t & 63;
  const int wave = t >> 6;  // 0..7 : owns codes 128*wave .. +127
  const int lo16 = lane & 15;
  const int hi = lane >> 4;
  const long rowBase = (long)blockIdx.x * RPB;

  // ---- B prologue: 128 codes/wave -> registers (64 x 16B coalesced loads/lane) ----
  long b[8][8];
  float nrm[8];
  {
    const char* cbB = (const char*)cbh;
#pragma unroll
    for (int n = 0; n < 8; ++n) {
      const int code = wave * 128 + n * 16 + lo16;
      const char* src = cbB + (long)code * 256 + hi * 64;
#pragma unroll
      for (int kp = 0; kp < 4; ++kp) {
        i64x2 bb = *(const i64x2*)(src + kp * 16);
        b[n][2 * kp] = bb.x;
        b[n][2 * kp + 1] = bb.y;
      }
      nrm[n] = norms_g[code];
    }
  }

  // ---- X stage mapping: thread t -> row srow (of 16), chunk sch (8 k-elems).
  // LDS layout = MFMA A-frag permuted order (chunk c -> (c&3)*64 + (c>>2)*8),
  // XOR-swizzled by (row&7)<<3 for bank spread. b64 granularity throughout.
  const int srow = t >> 5;  // 0..15
  const int sch = t & 31;   // 0..31
  const unsigned sdst =
      (unsigned)(srow * 256 + ((((sch & 3) * 64) + ((sch >> 2) * 8)) ^ ((srow & 7) << 3)));
  const f32x4* xv = (const f32x4*)(X + (rowBase + srow) * 256) + sch * 2;

  float xn = 0.f;
  f32x4 p0, p1;

#define CVT_WRITE(BUF)                                                                    \
  {                                                                                       \
    float s0 = 0.f;                                                                       \
    _Pragma("unroll") for (int j = 0; j < 4; ++j) s0 = __builtin_fmaf(p0[j], p0[j], s0);  \
    _Pragma("unroll") for (int j = 0; j < 4; ++j) s0 = __builtin_fmaf(p1[j], p1[j], s0);  \
    xn += s0;                                                                             \
    unsigned w0 = __builtin_amdgcn_cvt_pk_fp8_f32(p0[0], p0[1], 0, false);                \
    w0 = __builtin_amdgcn_cvt_pk_fp8_f32(p0[2], p0[3], w0, true);                         \
    unsigned w1 = __builtin_amdgcn_cvt_pk_fp8_f32(p1[0], p1[1], 0, false);                \
    w1 = __builtin_amdgcn_cvt_pk_fp8_f32(p1[2], p1[3], w1, true);                         \
    *(long*)((char*)&Xs[BUF][0] + sdst) = (long)(unsigned)w0 | ((long)w1 << 32);          \
  }

  // prologue: tile0 load+cvt+write; issue tile1 loads
  p0 = __builtin_nontemporal_load(xv);
  p1 = __builtin_nontemporal_load(xv + 1);
  CVT_WRITE(0);
  p0 = __builtin_nontemporal_load(xv + 1024);
  p1 = __builtin_nontemporal_load(xv + 1024 + 1);
  __syncthreads();

  for (int tt = 0; tt < NTILE; ++tt) {
    // ---- compute tile tt from Xs[tt&1] ----
    const char* xb = (const char*)&Xs[tt & 1][0];
    const unsigned abase = (unsigned)(lo16 * 256 + hi * 64);
    const unsigned aswz = (unsigned)((lo16 & 7) << 3);
    long a[8];
#pragma unroll
    for (int ks = 0; ks < 8; ++ks)
      a[ks] = *(const long*)(xb + ((abase + ks * 8) ^ aswz));

    f32x4 acc[8];
#pragma unroll
    for (int n = 0; n < 8; ++n) {
      f32x4 z = {0.f, 0.f, 0.f, 0.f};
      acc[n] = z;
    }
    __builtin_amdgcn_s_setprio(1);
#pragma unroll
    for (int ks = 0; ks < 8; ++ks)
#pragma unroll
      for (int n = 0; n < 8; ++n)
        acc[n] = __builtin_amdgcn_mfma_f32_16x16x32_fp8_fp8(a[ks], b[n][ks], acc[n], 0, 0, 0);
    __builtin_amdgcn_s_setprio(0);

    // score'' = ||e''||^2 - 2S*(x''.e''_dec); pack (monotone & ~1023) | global_code
    unsigned bst[4] = {0xFFFFFFFFu, 0xFFFFFFFFu, 0xFFFFFFFFu, 0xFFFFFFFFu};
#pragma unroll
    for (int n = 0; n < 8; ++n) {
      const float nf = nrm[n];
      const unsigned code = (unsigned)(wave * 128 + n * 16 + lo16);
#pragma unroll
      for (int r = 0; r < 4; ++r) {
        float sv = __builtin_fmaf(NEG2S, acc[n][r], nf);
        unsigned u = __float_as_uint(sv);
        u = ((int)u < 0) ? ~u : (u | 0x80000000u);
        bst[r] = umin2(bst[r], (u & 0xFFFFFC00u) | code);
      }
    }
    // butterfly over the 16 code-lanes; row_in_tile = hi*4 + r (C/D layout)
#pragma unroll
    for (int r = 0; r < 4; ++r) {
#pragma unroll
      for (int msk = 1; msk < 16; msk <<= 1)
        bst[r] = umin2(bst[r], (unsigned)__shfl_xor((int)bst[r], msk));
    }
    if (lo16 == 0) {
#pragma unroll
      for (int r = 0; r < 4; ++r) mgAll[tt][wave][hi * 4 + r] = bst[r];
    }

    // ---- stage tile tt+1 (cvt uses loads issued last iter); issue loads tt+2 ----
    if (tt + 1 < NTILE) {
      CVT_WRITE((tt + 1) & 1);
      if (tt + 2 < NTILE) {
        p0 = __builtin_nontemporal_load(xv + (tt + 2) * 1024);
        p1 = __builtin_nontemporal_load(xv + (tt + 2) * 1024 + 1);
      }
    }
    __syncthreads();
  }

  // ---- block-wide ||x||^2 partial ----
#pragma unroll
  for (int msk = 1; msk < 64; msk <<= 1) xn += __shfl_xor(xn, msk);
  if (lane == 0) wsumX[wave] = xn;

  // ---- final 8-way cross-wave merge per row + analytic loss term ----
  float scv = 0.f;
  if (t < RPB) {
    unsigned e = 0xFFFFFFFFu;
#pragma unroll
    for (int w = 0; w < 8; ++w) e = umin2(e, mgAll[t >> 4][w][t & 15]);
    idxArr[t] = e & 1023u;
    unsigned um = (e & 0xFFFFFC00u) | 512u;  // midpoint of truncated key
    float sr = (um & 0x80000000u) ? __uint_as_float(um & 0x7FFFFFFFu) : __uint_as_float(~um);
    scv = sr * INV_S2;
  }
#pragma unroll
  for (int msk = 1; msk < 64; msk <<= 1) scv += __shfl_xor(scv, msk);
  if (lane == 0) wsumS[wave] = scv;
  __syncthreads();

  // ---- gather fp32 codebook rows -> output (non-temporal store) ----
  {
    const f32x4* CBv = (const f32x4*)CB;
    f32x4* Og = (f32x4*)(out + rowBase * 256);
#pragma unroll 4
    for (int i = 0; i < 32; ++i) {
      int idx = t + NTHR * i;
      int row = idx >> 6, d4 = idx & 63;
      int code = (int)idxArr[row];
      f32x4 e = CBv[code * 64 + d4];
      __builtin_nontemporal_store(e, Og + idx);
    }
  }

  if (t == 0) {
    float tot = 0.f;
#pragma unroll
    for (int w = 0; w < 8; ++w) tot += wsumX[w] + wsumS[w];
    atomicAdd(loss_out, tot * lscale);
  }
}

extern "C" void kernel_launch(void* const* d_in, const int* in_sizes, int n_in,
                              void* d_out, int out_size, void* d_ws, size_t ws_size,
                              hipStream_t stream) {
  const float* X = (const float*)d_in[0];
  const float* CB = (const float*)d_in[1];
  float* out = (float*)d_out;

  const int ND = in_sizes[0];       // 16*4096*256 = 16777216
  const int K = in_sizes[1] / 256;  // 1024
  const int N = ND / 256;           // 65536

  float* ws_norms = (float*)d_ws;                               // K fp32 (4 KiB)
  unsigned char* ws_cb = (unsigned char*)((char*)d_ws + 4096);  // K*D fp8 (permuted)
  float* loss_out = out + (size_t)ND;

  vq_prep<<<K / 4, 256, 0, stream>>>(CB, ws_norms, ws_cb, loss_out);

  const float lscale = 1.25f / (float)ND;
  vq_main<<<N / RPB, NTHR, 0, stream>>>(X, CB, ws_norms, ws_cb, out, loss_out, lscale);
}